// Round 1
// baseline (9220.539 us; speedup 1.0000x reference)
//
#include <hip/hip_runtime.h>
#include <stdint.h>

// FPS: B=8, C=3, N=131072, S=2048 (from setup_inputs).
// 8 blocks per batch x 1024 threads; each thread owns 16 points (coords +
// running min-dist entirely in registers). Per round: register update pass,
// wave shfl reduction, block LDS reduction, cross-block exchange via packed
// u64 slots (agent-scope atomics) with a 12-bit round tag (S<=2048 => unique,
// parity-2 slot reuse is safe because a block only writes round t after
// having observed ALL partials of round t-1).

#define BATCHES 8
#define NPTS    131072
#define KBLK    8                      // blocks per batch
#define TPB     1024
#define NWAVE   (TPB / 64)
#define PPT     (NPTS / (KBLK * TPB))  // 16 points per thread

__global__ __launch_bounds__(TPB) void fps_kernel(
    const float* __restrict__ pts, float* __restrict__ out,
    unsigned long long* __restrict__ part, int S)
{
    const int gb  = blockIdx.x;      // 0..63
    const int b   = gb / KBLK;       // batch
    const int blk = gb % KBLK;       // block within batch
    const int tid = threadIdx.x;

    const float* X = pts + (size_t)(b * 3 + 0) * NPTS;
    const float* Y = pts + (size_t)(b * 3 + 1) * NPTS;
    const float* Z = pts + (size_t)(b * 3 + 2) * NPTS;
    float* outb = out + (size_t)b * 3 * S;

    const int base = blk * (NPTS / KBLK) + tid;   // owned indices: base + k*TPB

    // Register-resident coords + running min-dist.
    float px[PPT], py[PPT], pz[PPT], md[PPT];
#pragma unroll
    for (int k = 0; k < PPT; ++k) {
        int gi = base + k * TPB;
        px[k] = X[gi];
        py[k] = Y[gi];
        pz[k] = Z[gi];
        md[k] = 1e10f;
    }

    __shared__ int   s_far;
    __shared__ float s_wv[NWAVE];
    __shared__ int   s_wi[NWAVE];
    if (tid == 0) s_far = 0;     // reference starts at index 0
    __syncthreads();

    for (int t = 0; t < S; ++t) {
        const int far = s_far;

        // Emit selected point coords (reference emits BEFORE the update).
        if (blk == 0 && tid < 3) {
            const float* A = pts + (size_t)(b * 3 + tid) * NPTS;
            outb[(size_t)tid * S + t] = A[far];
        }
        if (t == S - 1) break;   // last selection needs no further update

        const float cx = X[far];
        const float cy = Y[far];
        const float cz = Z[far];

        // Update min-dist + thread-local argmax (ascending index, strict >).
        float bv = -1.0f;
        int   bi = 0x7FFFFFFF;
#pragma unroll
        for (int k = 0; k < PPT; ++k) {
            float dx = __fsub_rn(px[k], cx);
            float dy = __fsub_rn(py[k], cy);
            float dz = __fsub_rn(pz[k], cz);
            // numpy/jax order: (dx*dx + dy*dy) + dz*dz, no FMA contraction
            float d  = __fadd_rn(__fadd_rn(__fmul_rn(dx, dx), __fmul_rn(dy, dy)),
                                 __fmul_rn(dz, dz));
            float m  = fminf(md[k], d);
            md[k] = m;
            if (m > bv) { bv = m; bi = base + k * TPB; }
        }

        // Wave butterfly reduction of (value desc, index asc).
#pragma unroll
        for (int off = 32; off >= 1; off >>= 1) {
            float ov = __shfl_xor(bv, off);
            int   oi = __shfl_xor(bi, off);
            if (ov > bv || (ov == bv && oi < bi)) { bv = ov; bi = oi; }
        }
        if ((tid & 63) == 0) { s_wv[tid >> 6] = bv; s_wi[tid >> 6] = bi; }
        __syncthreads();

        if (tid == 0) {
            // Block-level reduction over 16 wave winners.
            float v = s_wv[0];
            int   i = s_wi[0];
#pragma unroll
            for (int w = 1; w < NWAVE; ++w) {
                float ov = s_wv[w];
                int   oi = s_wi[w];
                if (ov > v || (ov == v && oi < i)) { v = ov; i = oi; }
            }
            const unsigned long long tag = (unsigned long long)(t + 1); // 1..2047
            unsigned long long packed =
                ((unsigned long long)__float_as_uint(v) << 32) |
                ((unsigned long long)(unsigned)i << 12) | tag;

            unsigned long long* slot =
                part + ((size_t)(t & 1) * BATCHES + b) * KBLK;

            __hip_atomic_store(&slot[blk], packed,
                               __ATOMIC_RELAXED, __HIP_MEMORY_SCOPE_AGENT);

            // Poll peers (one 64B line), then reduce the 8 partials.
            unsigned long long got[KBLK];
            for (;;) {
                bool ready = true;
#pragma unroll
                for (int k2 = 0; k2 < KBLK; ++k2) {
                    got[k2] = __hip_atomic_load(&slot[k2],
                                 __ATOMIC_RELAXED, __HIP_MEMORY_SCOPE_AGENT);
                    if ((got[k2] & 0xFFFull) != tag) ready = false;
                }
                if (ready) break;
                __builtin_amdgcn_s_sleep(2);
            }
            float bvv = -1.0f;
            int   bii = 0x7FFFFFFF;
#pragma unroll
            for (int k2 = 0; k2 < KBLK; ++k2) {
                float fv = __uint_as_float((unsigned)(got[k2] >> 32));
                int   ib = (int)((got[k2] >> 12) & 0x1FFFF);
                if (fv > bvv || (fv == bvv && ib < bii)) { bvv = fv; bii = ib; }
            }
            s_far = bii;
        }
        __syncthreads();
    }
}

extern "C" void kernel_launch(void* const* d_in, const int* in_sizes, int n_in,
                              void* d_out, int out_size, void* d_ws, size_t ws_size,
                              hipStream_t stream) {
    const float* pts = (const float*)d_in[0];
    float* out = (float*)d_out;
    unsigned long long* part = (unsigned long long*)d_ws;
    int S = out_size / (BATCHES * 3);   // 2048

    // Zero the 1 KiB sync-slot buffer (captured in the graph, replayed).
    hipMemsetAsync(d_ws, 0, (size_t)2 * BATCHES * KBLK * sizeof(unsigned long long),
                   stream);

    void* args[] = { (void*)&pts, (void*)&out, (void*)&part, (void*)&S };
    hipLaunchCooperativeKernel((const void*)fps_kernel,
                               dim3(BATCHES * KBLK), dim3(TPB),
                               args, 0, stream);
}

// Round 2
// 7335.204 us; speedup vs baseline: 1.2570x; 1.2570x over previous
//
#include <hip/hip_runtime.h>
#include <stdint.h>

// FPS: B=8, C=3, N=131072, S=2048.
// 64 single-wave blocks per batch (512 blocks total, cooperative launch).
// batch = blockIdx % 8  -> all blocks of a batch land on ONE XCD (round-robin
// dispatch), so sync slots + the batch's coords stay in that XCD's L2.
// Each thread owns 32 points; coords + running min-dist entirely in registers.
// Per round: register update pass -> wave shfl butterfly (packed u64) ->
// lane0 posts slot -> all 64 lanes poll the 64 slots (one coalesced 512B load)
// -> second butterfly over the 64 partials. No __syncthreads, no LDS.
// Packed ordering: (valbits<<32) | ((0x1FFFF - idx)<<12) | tag ; u64 max ==
// (value desc, index asc) lexicographic, reproducing jnp.argmax first-match.

#define BATCHES 8
#define NPTS    131072
#define KBLK    64                 // blocks per batch (one wave each)
#define TPB     64
#define CHUNK   (NPTS / KBLK)      // 2048 points per block
#define PPT     (CHUNK / TPB)      // 32 points per thread

__global__ __launch_bounds__(TPB) void fps_kernel(
    const float* __restrict__ pts, float* __restrict__ out,
    unsigned long long* __restrict__ part, int S)
{
    const int gb   = blockIdx.x;
    const int b    = gb & (BATCHES - 1);   // batch = gb % 8  (co-XCD)
    const int blk  = gb >> 3;              // 0..63 within batch
    const int lane = threadIdx.x;

    const float* X = pts + (size_t)(b * 3 + 0) * NPTS;
    const float* Y = pts + (size_t)(b * 3 + 1) * NPTS;
    const float* Z = pts + (size_t)(b * 3 + 2) * NPTS;

    const int base = blk * CHUNK + lane;   // owned: base + k*TPB, k<PPT

    float px[PPT], py[PPT], pz[PPT], md[PPT];
#pragma unroll
    for (int k = 0; k < PPT; ++k) {
        int gi = base + k * TPB;
        px[k] = X[gi]; py[k] = Y[gi]; pz[k] = Z[gi];
        md[k] = 1e10f;
    }

    unsigned long long* const slotsP[2] = {
        part + (size_t)b * KBLK,                 // parity 0
        part + (size_t)(BATCHES + b) * KBLK      // parity 1
    };

    int far = 0;   // reference starts at index 0
    for (int t = 0; t < S; ++t) {
        // Emit selected point coords (reference emits BEFORE the update).
        if (blk == 0 && lane < 3) {
            const float* A = pts + (size_t)(b * 3 + lane) * NPTS;
            out[((size_t)b * 3 + lane) * S + t] = A[far];
        }
        if (t == S - 1) break;

        const float cx = X[far];
        const float cy = Y[far];
        const float cz = Z[far];

        // Update min-dist + thread-local argmax (ascending index, strict >).
        float bv = -1.0f;
        int   bi = 0x7FFFFFFF;
#pragma unroll
        for (int k = 0; k < PPT; ++k) {
            float dx = __fsub_rn(px[k], cx);
            float dy = __fsub_rn(py[k], cy);
            float dz = __fsub_rn(pz[k], cz);
            // numpy/jax order: (dx*dx + dy*dy) + dz*dz, no FMA contraction
            float d  = __fadd_rn(__fadd_rn(__fmul_rn(dx, dx), __fmul_rn(dy, dy)),
                                 __fmul_rn(dz, dz));
            float m  = fminf(md[k], d);
            md[k] = m;
            if (m > bv) { bv = m; bi = base + k * TPB; }
        }

        const unsigned long long tag = (unsigned long long)(t + 1); // 1..2047
        unsigned long long p =
            ((unsigned long long)__float_as_uint(bv) << 32) |
            ((unsigned long long)(unsigned)(0x1FFFF - bi) << 12) | tag;

        // Wave butterfly: u64 max == (value desc, index asc).
#pragma unroll
        for (int off = 32; off >= 1; off >>= 1) {
            unsigned long long o = __shfl_xor(p, off);
            if (o > p) p = o;
        }

        unsigned long long* slots = slotsP[t & 1];
        if (lane == 0)
            __hip_atomic_store(&slots[blk], p,
                               __ATOMIC_RELAXED, __HIP_MEMORY_SCOPE_AGENT);

        // Poll: lane i watches slot i (one coalesced 512B load per iteration).
        unsigned long long got;
        for (;;) {
            got = __hip_atomic_load(&slots[lane],
                                    __ATOMIC_RELAXED, __HIP_MEMORY_SCOPE_AGENT);
            if (__all((int)((got & 0xFFFull) == tag))) break;
            __builtin_amdgcn_s_sleep(1);
        }

        // Butterfly over the 64 block partials.
#pragma unroll
        for (int off = 32; off >= 1; off >>= 1) {
            unsigned long long o = __shfl_xor(got, off);
            if (o > got) got = o;
        }
        far = 0x1FFFF - (int)((got >> 12) & 0x1FFFF);
    }
}

extern "C" void kernel_launch(void* const* d_in, const int* in_sizes, int n_in,
                              void* d_out, int out_size, void* d_ws, size_t ws_size,
                              hipStream_t stream) {
    const float* pts = (const float*)d_in[0];
    float* out = (float*)d_out;
    unsigned long long* part = (unsigned long long*)d_ws;
    int S = out_size / (BATCHES * 3);   // 2048

    // Reset sync slots every replay (captured in the graph).
    hipMemsetAsync(d_ws, 0,
                   (size_t)2 * BATCHES * KBLK * sizeof(unsigned long long),
                   stream);

    void* args[] = { (void*)&pts, (void*)&out, (void*)&part, (void*)&S };
    hipLaunchCooperativeKernel((const void*)fps_kernel,
                               dim3(BATCHES * KBLK), dim3(TPB),
                               args, 0, stream);
}

// Round 3
// 5650.996 us; speedup vs baseline: 1.6317x; 1.2980x over previous
//
#include <hip/hip_runtime.h>
#include <stdint.h>

// FPS: B=8, C=3, N=131072, S=2048.
// 16 blocks x 256 threads per batch (128 blocks total, cooperative).
// batch = blockIdx % 8 -> all of a batch's blocks on ONE XCD (round-robin
// dispatch heuristic; correctness does not depend on it, only L2 locality).
// Each thread owns 32 points; coords + running min-dist in registers.
// Per round: register update -> wave shfl butterfly (packed u64) -> 4-wave
// LDS exchange -> block leader posts 1 of 16 slots (agent scope) -> all
// waves poll the 16 slots (2 cachelines) -> 4-step butterfly -> far.
// Packed: (valbits<<32) | ((0x1FFFF - idx)<<12) | tag ; u64 max ==
// (value desc, index asc), reproducing jnp.argmax first-match semantics.
// Output coords are emitted from the (L2-resident) gather every thread
// already does for the next update -- no extra serial work for block 0.

#define BATCHES 8
#define NPTS    131072
#define KBLK    16                  // blocks per batch
#define TPB     256
#define NWAVE   (TPB / 64)
#define CHUNK   (NPTS / KBLK)       // 8192 points per block
#define PPT     (CHUNK / TPB)       // 32 points per thread

__global__ __launch_bounds__(TPB) void fps_kernel(
    const float* __restrict__ pts, float* __restrict__ out,
    unsigned long long* __restrict__ part, int S)
{
    const int gb   = blockIdx.x;
    const int b    = gb & (BATCHES - 1);   // batch (co-XCD)
    const int blk  = gb >> 3;              // 0..15 within batch
    const int tid  = threadIdx.x;
    const int lane = tid & 63;
    const int wv   = tid >> 6;

    const float* X = pts + (size_t)(b * 3 + 0) * NPTS;
    const float* Y = pts + (size_t)(b * 3 + 1) * NPTS;
    const float* Z = pts + (size_t)(b * 3 + 2) * NPTS;

    const int base = blk * CHUNK + tid;    // owned: base + k*TPB, k<PPT

    float px[PPT], py[PPT], pz[PPT], md[PPT];
#pragma unroll
    for (int k = 0; k < PPT; ++k) {
        int gi = base + k * TPB;
        px[k] = X[gi]; py[k] = Y[gi]; pz[k] = Z[gi];
        md[k] = 1e10f;
    }

    __shared__ unsigned long long s_part[NWAVE];

    unsigned long long* const slotsP[2] = {
        part + (size_t)b * KBLK,                // parity 0
        part + (size_t)(BATCHES + b) * KBLK     // parity 1
    };

    // Round 0 selection is index 0 (reference). Gather its coords (L2-hot
    // after the register-load pass) and emit.
    float cx = X[0], cy = Y[0], cz = Z[0];
    if (blk == 0 && tid == 0) {
        out[((size_t)b * 3 + 0) * S + 0] = cx;
        out[((size_t)b * 3 + 1) * S + 0] = cy;
        out[((size_t)b * 3 + 2) * S + 0] = cz;
    }

    for (int t = 0; t < S - 1; ++t) {
        // --- update min-dist + thread-local argmax (ascending k, strict >) ---
        float bv = -1.0f;
        int   bi = 0x7FFFFFFF;
#pragma unroll
        for (int k = 0; k < PPT; ++k) {
            float dx = __fsub_rn(px[k], cx);
            float dy = __fsub_rn(py[k], cy);
            float dz = __fsub_rn(pz[k], cz);
            // numpy/jax order: (dx*dx + dy*dy) + dz*dz, no FMA contraction
            float d  = __fadd_rn(__fadd_rn(__fmul_rn(dx, dx), __fmul_rn(dy, dy)),
                                 __fmul_rn(dz, dz));
            float m  = fminf(md[k], d);
            md[k] = m;
            if (m > bv) { bv = m; bi = base + k * TPB; }
        }

        const unsigned long long tag = (unsigned long long)(t + 1); // 1..2047
        unsigned long long p =
            ((unsigned long long)__float_as_uint(bv) << 32) |
            ((unsigned long long)(unsigned)(0x1FFFF - bi) << 12) | tag;

        // --- wave butterfly: u64 max == (value desc, index asc) ---
#pragma unroll
        for (int off = 32; off >= 1; off >>= 1) {
            unsigned long long o = __shfl_xor(p, off);
            if (o > p) p = o;
        }

        // --- cross-wave exchange (4 partials in LDS) ---
        if (lane == 0) s_part[wv] = p;
        __syncthreads();
        unsigned long long bp = s_part[0];
#pragma unroll
        for (int w = 1; w < NWAVE; ++w) {
            unsigned long long o = s_part[w];
            if (o > bp) bp = o;
        }
        __syncthreads();   // protects s_part against next round's overwrite

        // --- post block partial, poll the batch's 16 slots ---
        unsigned long long* slots = slotsP[t & 1];
        if (tid == 0)
            __hip_atomic_store(&slots[blk], bp,
                               __ATOMIC_RELAXED, __HIP_MEMORY_SCOPE_AGENT);

        unsigned long long got;
        for (;;) {
            got = __hip_atomic_load(&slots[lane & (KBLK - 1)],
                                    __ATOMIC_RELAXED, __HIP_MEMORY_SCOPE_AGENT);
            if (__all((int)((got & 0xFFFull) == tag))) break;
        }

        // --- butterfly over the 16 partials (replicated 4x across 64 lanes) ---
#pragma unroll
        for (int off = 8; off >= 1; off >>= 1) {
            unsigned long long o = __shfl_xor(got, off);
            if (o > got) got = o;
        }
        const int far = 0x1FFFF - (int)((got >> 12) & 0x1FFFF);

        // --- gather next center (L2-resident) + emit output (reused loads) ---
        cx = X[far]; cy = Y[far]; cz = Z[far];
        if (blk == 0 && tid == 0) {
            out[((size_t)b * 3 + 0) * S + (t + 1)] = cx;
            out[((size_t)b * 3 + 1) * S + (t + 1)] = cy;
            out[((size_t)b * 3 + 2) * S + (t + 1)] = cz;
        }
    }
}

extern "C" void kernel_launch(void* const* d_in, const int* in_sizes, int n_in,
                              void* d_out, int out_size, void* d_ws, size_t ws_size,
                              hipStream_t stream) {
    const float* pts = (const float*)d_in[0];
    float* out = (float*)d_out;
    unsigned long long* part = (unsigned long long*)d_ws;
    int S = out_size / (BATCHES * 3);   // 2048

    // Reset sync slots every replay (captured in the graph).
    hipMemsetAsync(d_ws, 0,
                   (size_t)2 * BATCHES * KBLK * sizeof(unsigned long long),
                   stream);

    void* args[] = { (void*)&pts, (void*)&out, (void*)&part, (void*)&S };
    hipLaunchCooperativeKernel((const void*)fps_kernel,
                               dim3(BATCHES * KBLK), dim3(TPB),
                               args, 0, stream);
}